// Round 1
// baseline (137.173 us; speedup 1.0000x reference)
//
#include <hip/hip_runtime.h>
#include <hip/hip_bf16.h>

// ConvolutionalAttention2D: B=16, C=256, N=H*W=4096.
// out = (Wo * (phiQ @ phiV^T)) @ phiK + bo, phiX = elu(Wx @ x)+1
// All heavy GEMMs in bf16 MFMA (16x16x32), fp32 accumulate.

typedef short  bf16x8 __attribute__((ext_vector_type(8)));
typedef float  f32x4  __attribute__((ext_vector_type(4)));
typedef unsigned short u16x4 __attribute__((ext_vector_type(4)));

#define NB 16
#define NC 256
#define NN 4096

__device__ __forceinline__ unsigned short f2bf(float f) {
    union { float f; unsigned u; } v; v.f = f;
    unsigned r = v.u + 0x7FFFu + ((v.u >> 16) & 1u);
    return (unsigned short)(r >> 16);
}

__device__ __forceinline__ float phi_act(float v) {
    return v > 0.f ? v + 1.f : __expf(v);
}

// ---------------------------------------------------------------------------
// 128x128-tile NT GEMM: D[r][c] = sum_k A[r][k] * BT[c][k], k in [k0, k0+64*nk)
// block = 256 threads (4 waves); wave w owns 64x64 sub-tile (wr=(w>>1)*64, wc=(w&1)*64)
// acc[m][n] frag: rows wr+m*16+(lane>>4)*4+i, cols wc+n*16+(lane&15)
// LDS: k-slab-major 16B units with +1 pad: unit(s,r) = s*129+r  (bank-free both sides)
// ---------------------------------------------------------------------------
__device__ __forceinline__ void gemm128_nt(
    const unsigned short* __restrict__ A, int lda,
    const unsigned short* __restrict__ BT, int ldb,
    int k0, int nk, f32x4 (&acc)[4][4])
{
    __shared__ bf16x8 lsA[1032];
    __shared__ bf16x8 lsB[1032];
    const int t    = threadIdx.x;
    const int lane = t & 63;
    const int sr   = t >> 2;          // staging row 0..63 (plus +64)
    const int ss   = (t & 3) * 2;     // staging slab pair 0,2,4,6
    const int w    = t >> 6;
    const int wr   = (w >> 1) * 64;
    const int wc   = (w & 1) * 64;
    const int q    = lane >> 4;       // quarter 0..3
    const int c15  = lane & 15;

    for (int kt = 0; kt < nk; ++kt) {
        const int kb = k0 + kt * 64;
        // global -> regs (before barrier: overlaps with previous MFMAs)
        bf16x8 ra[4], rb[4];
        #pragma unroll
        for (int j = 0; j < 2; ++j) {
            const int r = sr + 64 * j;
            const bf16x8* ga = (const bf16x8*)(A + (size_t)r * lda + kb) + ss;
            ra[2 * j]     = ga[0];
            ra[2 * j + 1] = ga[1];
            const bf16x8* gb = (const bf16x8*)(BT + (size_t)r * ldb + kb) + ss;
            rb[2 * j]     = gb[0];
            rb[2 * j + 1] = gb[1];
        }
        if (kt) __syncthreads();      // previous compute done before overwrite
        #pragma unroll
        for (int j = 0; j < 2; ++j) {
            const int r = sr + 64 * j;
            lsA[(ss    ) * 129 + r] = ra[2 * j];
            lsA[(ss + 1) * 129 + r] = ra[2 * j + 1];
            lsB[(ss    ) * 129 + r] = rb[2 * j];
            lsB[(ss + 1) * 129 + r] = rb[2 * j + 1];
        }
        __syncthreads();
        #pragma unroll
        for (int g = 0; g < 2; ++g) { // kk = g*32
            const int sb = (g * 4 + q) * 129;
            bf16x8 af[4], bfr[4];
            #pragma unroll
            for (int m = 0; m < 4; ++m) af[m]  = lsA[sb + wr + m * 16 + c15];
            #pragma unroll
            for (int n = 0; n < 4; ++n) bfr[n] = lsB[sb + wc + n * 16 + c15];
            #pragma unroll
            for (int m = 0; m < 4; ++m)
                #pragma unroll
                for (int n = 0; n < 4; ++n)
                    acc[m][n] = __builtin_amdgcn_mfma_f32_16x16x32_bf16(
                        af[m], bfr[n], acc[m][n], 0, 0, 0);
        }
    }
}

// --------------------------- K0a: weights -> bf16 ---------------------------
__global__ __launch_bounds__(256) void k_wconv(
    const float* __restrict__ Wq, const float* __restrict__ Wk,
    const float* __restrict__ Wv, const float* __restrict__ Wo,
    unsigned short* __restrict__ Wqkv, unsigned short* __restrict__ Wob)
{
    int i = blockIdx.x * 256 + threadIdx.x;        // 262144 total
    if      (i < 65536)  Wqkv[i] = f2bf(Wq[i]);
    else if (i < 131072) Wqkv[i] = f2bf(Wk[i - 65536]);
    else if (i < 196608) Wqkv[i] = f2bf(Wv[i - 131072]);
    else if (i < 262144) Wob[i - 196608] = f2bf(Wo[i - 196608]);
}

// ------------------- K0b: x[b][c][n] f32 -> xT[b][n][c] bf16 ----------------
__global__ __launch_bounds__(256) void k_xpose(
    const float* __restrict__ x, unsigned short* __restrict__ xT)
{
    __shared__ float tile[32][33];
    const int b  = blockIdx.z;
    const int n0 = blockIdx.x * 32, c0 = blockIdx.y * 32;
    const int tx = threadIdx.x, ty = threadIdx.y;
    const float* xp = x + ((size_t)b * NC + c0) * NN + n0;
    #pragma unroll
    for (int j = 0; j < 4; ++j)
        tile[ty + 8 * j][tx] = xp[(size_t)(ty + 8 * j) * NN + tx];
    __syncthreads();
    unsigned short* op = xT + ((size_t)b * NN + n0) * NC + c0;
    #pragma unroll
    for (int j = 0; j < 4; ++j)
        op[(size_t)(ty + 8 * j) * NC + tx] = f2bf(tile[tx][ty + 8 * j]);
}

// ------ K1: [phiQ;phiK^T;phiV] = phi(Wqkv @ x) ; grid = 16*6*32 -------------
__global__ __launch_bounds__(256) void k_proj(
    const unsigned short* __restrict__ Wqkv, const unsigned short* __restrict__ xT,
    unsigned short* __restrict__ phiQ, unsigned short* __restrict__ phiKT,
    unsigned short* __restrict__ phiV)
{
    const int bid = blockIdx.x;
    const int nt  = bid & 31;
    const int mt  = (bid >> 5) % 6;
    const int b   = bid / 192;
    const unsigned short* A  = Wqkv + mt * 128 * NC;
    const unsigned short* BT = xT + ((size_t)b * NN + nt * 128) * NC;
    f32x4 acc[4][4] = {};
    gemm128_nt(A, NC, BT, NC, 0, 4, acc);

    const int lane = threadIdx.x & 63;
    const int w    = threadIdx.x >> 6;
    const int wr   = (w >> 1) * 64, wc = (w & 1) * 64;
    const int q4   = (lane >> 4) * 4, c15 = lane & 15;
    const int p    = mt >> 1;                 // 0=Q, 1=K, 2=V
    const int rp0  = (mt & 1) * 128 + wr + q4;
    const int cb   = nt * 128 + wc + c15;
    if (p == 1) {
        // phiK stored transposed [n][c]: regs span rows -> packed 8B stores
        unsigned short* dst = phiKT + (size_t)b * NN * NC;
        #pragma unroll
        for (int m = 0; m < 4; ++m)
            #pragma unroll
            for (int n = 0; n < 4; ++n) {
                u16x4 pk;
                #pragma unroll
                for (int i = 0; i < 4; ++i) pk[i] = f2bf(phi_act(acc[m][n][i]));
                *(u16x4*)(dst + (size_t)(cb + n * 16) * NC + rp0 + m * 16) = pk;
            }
    } else {
        unsigned short* dst = (p == 0 ? phiQ : phiV) + (size_t)b * NC * NN;
        #pragma unroll
        for (int m = 0; m < 4; ++m)
            #pragma unroll
            for (int i = 0; i < 4; ++i) {
                unsigned short* rowp = dst + (size_t)(rp0 + m * 16 + i) * NN + cb;
                #pragma unroll
                for (int n = 0; n < 4; ++n)
                    rowp[n * 16] = f2bf(phi_act(acc[m][n][i]));
            }
    }
}

// ------ K2: qvT_part[s][b][d][c] = phiQ@phiV^T partial (split-K=4) ----------
__global__ __launch_bounds__(256) void k_qv(
    const unsigned short* __restrict__ phiQ, const unsigned short* __restrict__ phiV,
    float* __restrict__ qvTp)
{
    const int bid = blockIdx.x;                    // 256 blocks
    const int s = bid & 3, nt = (bid >> 2) & 1, mt = (bid >> 3) & 1, b = bid >> 4;
    const unsigned short* A  = phiQ + ((size_t)b * NC + mt * 128) * NN;
    const unsigned short* BT = phiV + ((size_t)b * NC + nt * 128) * NN;
    f32x4 acc[4][4] = {};
    gemm128_nt(A, NN, BT, NN, s * 1024, 16, acc);

    const int lane = threadIdx.x & 63, w = threadIdx.x >> 6;
    const int wr = (w >> 1) * 64, wc = (w & 1) * 64;
    const int q4 = (lane >> 4) * 4, c15 = lane & 15;
    float* dst = qvTp + (((size_t)s * NB + b) << 16);
    const int c0 = mt * 128 + wr + q4;
    const int d0 = nt * 128 + wc + c15;
    #pragma unroll
    for (int m = 0; m < 4; ++m)
        #pragma unroll
        for (int n = 0; n < 4; ++n)
            *(f32x4*)(dst + (size_t)(d0 + n * 16) * NC + c0 + m * 16) = acc[m][n];
}

// ------ K2b: qvT[b][d][c] bf16 = sum_s partials -----------------------------
__global__ __launch_bounds__(256) void k_qvred(
    const float* __restrict__ p, unsigned short* __restrict__ qvT)
{
    const size_t i = (size_t)blockIdx.x * 256 + threadIdx.x;  // 262144 f32x4 units
    const f32x4* pv = (const f32x4*)p;
    f32x4 v = pv[i];
    v = v + pv[i + 262144];
    v = v + pv[i + 2 * 262144];
    v = v + pv[i + 3 * 262144];
    u16x4 o;
    #pragma unroll
    for (int j = 0; j < 4; ++j) o[j] = f2bf(v[j]);
    ((u16x4*)qvT)[i] = o;
}

// ------ K3: M[b][o][d] = Wo @ qv  (A=Wo_bf, BT=qvT[b]) -----------------------
__global__ __launch_bounds__(256) void k_mproj(
    const unsigned short* __restrict__ Wob, const unsigned short* __restrict__ qvT,
    unsigned short* __restrict__ Mb)
{
    const int bid = blockIdx.x;                    // 64 blocks
    const int nt = bid & 1, mt = (bid >> 1) & 1, b = bid >> 2;
    const unsigned short* A  = Wob + mt * 128 * NC;
    const unsigned short* BT = qvT + ((size_t)b << 16) + nt * 128 * NC;
    f32x4 acc[4][4] = {};
    gemm128_nt(A, NC, BT, NC, 0, 4, acc);

    const int lane = threadIdx.x & 63, w = threadIdx.x >> 6;
    const int wr = (w >> 1) * 64, wc = (w & 1) * 64;
    const int q4 = (lane >> 4) * 4, c15 = lane & 15;
    unsigned short* dst = Mb + ((size_t)b << 16);
    const int o0 = mt * 128 + wr + q4;
    const int d0 = nt * 128 + wc + c15;
    #pragma unroll
    for (int m = 0; m < 4; ++m)
        #pragma unroll
        for (int i = 0; i < 4; ++i) {
            const int row = o0 + m * 16 + i;
            #pragma unroll
            for (int n = 0; n < 4; ++n)
                dst[(size_t)row * NC + d0 + n * 16] = f2bf(acc[m][n][i]);
        }
}

// ------ K4: out[b][o][n] = M[b] @ phiK + bo ----------------------------------
__global__ __launch_bounds__(256) void k_out(
    const unsigned short* __restrict__ Mb, const unsigned short* __restrict__ phiKT,
    const float* __restrict__ bo, float* __restrict__ out)
{
    const int bid = blockIdx.x;                    // 1024 blocks
    const int nt = bid & 31, mt = (bid >> 5) & 1, b = bid >> 6;
    const unsigned short* A  = Mb + ((size_t)b << 16) + mt * 128 * NC;
    const unsigned short* BT = phiKT + (size_t)b * NN * NC + (size_t)nt * 128 * NC;
    f32x4 acc[4][4] = {};
    gemm128_nt(A, NC, BT, NC, 0, 4, acc);

    const int lane = threadIdx.x & 63, w = threadIdx.x >> 6;
    const int wr = (w >> 1) * 64, wc = (w & 1) * 64;
    const int q4 = (lane >> 4) * 4, c15 = lane & 15;
    float* dst = out + (size_t)b * NC * NN;
    const int o0 = mt * 128 + wr + q4;
    const int n0 = nt * 128 + wc + c15;
    #pragma unroll
    for (int m = 0; m < 4; ++m)
        #pragma unroll
        for (int i = 0; i < 4; ++i) {
            const int row  = o0 + m * 16 + i;
            const float bb = bo[row];
            #pragma unroll
            for (int n = 0; n < 4; ++n)
                dst[(size_t)row * NN + n0 + n * 16] = acc[m][n][i] + bb;
        }
}

// ---------------------------------------------------------------------------
extern "C" void kernel_launch(void* const* d_in, const int* in_sizes, int n_in,
                              void* d_out, int out_size, void* d_ws, size_t ws_size,
                              hipStream_t stream)
{
    (void)in_sizes; (void)n_in; (void)out_size; (void)ws_size;
    const float* x  = (const float*)d_in[0];
    const float* Wq = (const float*)d_in[1];
    const float* Wk = (const float*)d_in[2];
    const float* Wv = (const float*)d_in[3];
    const float* Wo = (const float*)d_in[4];
    const float* bo = (const float*)d_in[5];
    float* out = (float*)d_out;

    char* ws = (char*)d_ws;
    size_t off = 0;
    auto alloc = [&](size_t bytes) {
        void* p = ws + off;
        off += (bytes + 255) & ~(size_t)255;
        return p;
    };
    unsigned short* xT    = (unsigned short*)alloc((size_t)NB * NN * NC * 2); // 32 MiB
    unsigned short* phiQ  = (unsigned short*)alloc((size_t)NB * NC * NN * 2); // 32 MiB
    unsigned short* phiV  = (unsigned short*)alloc((size_t)NB * NC * NN * 2); // 32 MiB
    unsigned short* phiKT = (unsigned short*)alloc((size_t)NB * NN * NC * 2); // 32 MiB
    float*          qvTp  = (float*)alloc((size_t)4 * NB * NC * NC * 4);      // 16 MiB
    unsigned short* qvT   = (unsigned short*)alloc((size_t)NB * NC * NC * 2); //  2 MiB
    unsigned short* Mb    = (unsigned short*)alloc((size_t)NB * NC * NC * 2); //  2 MiB
    unsigned short* Wqkv  = (unsigned short*)alloc((size_t)768 * NC * 2);
    unsigned short* Wob   = (unsigned short*)alloc((size_t)NC * NC * 2);

    k_wconv<<<1024, 256, 0, stream>>>(Wq, Wk, Wv, Wo, Wqkv, Wob);
    k_xpose<<<dim3(NN / 32, NC / 32, NB), dim3(32, 8), 0, stream>>>(x, xT);
    k_proj<<<NB * 6 * 32, 256, 0, stream>>>(Wqkv, xT, phiQ, phiKT, phiV);
    k_qv<<<NB * 2 * 2 * 4, 256, 0, stream>>>(phiQ, phiV, qvTp);
    k_qvred<<<1024, 256, 0, stream>>>(qvTp, qvT);
    k_mproj<<<NB * 2 * 2, 256, 0, stream>>>(Wob, qvT, Mb);
    k_out<<<NB * 2 * 32, 256, 0, stream>>>(Mb, phiKT, bo, out);
}

// Round 2
// 126.398 us; speedup vs baseline: 1.0853x; 1.0853x over previous
//
#include <hip/hip_runtime.h>
#include <hip/hip_bf16.h>

// ConvolutionalAttention2D: B=16, C=256, N=H*W=4096.
// out = (Wo * (phiQ @ phiV^T)) @ phiK + bo, phiX = elu(Wx @ x)+1
// bf16 MFMA (16x16x32), fp32 accumulate, global_load_lds staging + XOR swizzle.

typedef short  bf16x8 __attribute__((ext_vector_type(8)));
typedef float  f32x4  __attribute__((ext_vector_type(4)));
typedef unsigned short u16x4 __attribute__((ext_vector_type(4)));

#define NB 16
#define NC 256
#define NN 4096

__device__ __forceinline__ unsigned short f2bf(float f) {
    union { float f; unsigned u; } v; v.f = f;
    unsigned r = v.u + 0x7FFFu + ((v.u >> 16) & 1u);
    return (unsigned short)(r >> 16);
}

__device__ __forceinline__ float phi_act(float v) {
    return v > 0.f ? v + 1.f : __expf(v);
}

__device__ __forceinline__ void gload_lds16(const void* g, void* l) {
    __builtin_amdgcn_global_load_lds(
        (const __attribute__((address_space(1))) void*)g,
        (__attribute__((address_space(3))) void*)l, 16, 0, 0);
}

// Stage a 128row x 64k bf16 tile (16 KB) into linear LDS with XOR-swizzled
// SOURCE address (so swizzled reads see correct data; rule both-sides).
// LDS unit u (16B) = row*8 + kslot; thread t issue i -> u = i*256 + t.
__device__ __forceinline__ void stage_tile(
    const unsigned short* __restrict__ src, int ld, int kb, char* lds, int t)
{
    const int kslot  = t & 7;
    const int rbase  = t >> 3;                         // 0..31
    const int srcOff = (kslot * 16) ^ ((rbase & 7) << 4);
    const int wbase  = (t >> 6) * 1024;                // wave-uniform
    #pragma unroll
    for (int i = 0; i < 4; ++i) {
        const int r = i * 32 + rbase;
        const char* g = (const char*)(src + (size_t)r * ld + kb) + srcOff;
        gload_lds16(g, lds + i * 4096 + wbase);
    }
}

// Swizzled fragment read: row-major [128][64] bf16, byte ^= ((row&7)<<4)
__device__ __forceinline__ bf16x8 frag_ld(const char* lds, int row, int kbyte) {
    return *(const bf16x8*)(lds + row * 128 + (kbyte ^ ((row & 7) << 4)));
}

// 128x128 NT GEMM tile: D[r][c] = sum_k A[r][k]*BT[c][k], k in [k0,k0+64*nk)
// 4 waves; wave w: (wr,wc) = ((w>>1)*64,(w&1)*64); frag grid 4x4 of 16x16.
// SWAP=false: acc[m][n] rows = A-dir (wr+m*16+q4+i), cols = B-dir (wc+n*16+c15)
// SWAP=true : acc[m][n] rows = B-dir (wc+n*16+q4+i), cols = A-dir (wr+m*16+c15)
template<bool SWAP>
__device__ __forceinline__ void gemm128(
    const unsigned short* __restrict__ A, int lda,
    const unsigned short* __restrict__ BT, int ldb,
    int k0, int nk, char* lsA, char* lsB, f32x4 (&acc)[4][4])
{
    const int t = threadIdx.x;
    const int lane = t & 63;
    const int w  = t >> 6;
    const int wr = (w >> 1) * 64, wc = (w & 1) * 64;
    const int q  = lane >> 4, c15 = lane & 15;

    for (int kt = 0; kt < nk; ++kt) {
        const int kb = k0 + kt * 64;
        if (kt) __syncthreads();            // prior reads done before overwrite
        stage_tile(A,  lda, kb, lsA, t);
        stage_tile(BT, ldb, kb, lsB, t);
        __syncthreads();                    // compiler drains vmcnt before barrier
        #pragma unroll
        for (int g = 0; g < 2; ++g) {
            const int kbyte = g * 64 + q * 16;
            bf16x8 af[4], bfr[4];
            #pragma unroll
            for (int m = 0; m < 4; ++m) af[m]  = frag_ld(lsA, wr + m * 16 + c15, kbyte);
            #pragma unroll
            for (int n = 0; n < 4; ++n) bfr[n] = frag_ld(lsB, wc + n * 16 + c15, kbyte);
            #pragma unroll
            for (int m = 0; m < 4; ++m)
                #pragma unroll
                for (int n = 0; n < 4; ++n)
                    acc[m][n] = SWAP
                        ? __builtin_amdgcn_mfma_f32_16x16x32_bf16(bfr[n], af[m], acc[m][n], 0, 0, 0)
                        : __builtin_amdgcn_mfma_f32_16x16x32_bf16(af[m], bfr[n], acc[m][n], 0, 0, 0);
        }
    }
}

// --------------------------- K0a: weights -> bf16 ---------------------------
__global__ __launch_bounds__(256) void k_wconv(
    const float* __restrict__ Wq, const float* __restrict__ Wk,
    const float* __restrict__ Wv, const float* __restrict__ Wo,
    unsigned short* __restrict__ Wqkv, unsigned short* __restrict__ Wob)
{
    int i = blockIdx.x * 256 + threadIdx.x;        // 262144 total
    if      (i < 65536)  Wqkv[i] = f2bf(Wq[i]);
    else if (i < 131072) Wqkv[i] = f2bf(Wk[i - 65536]);
    else if (i < 196608) Wqkv[i] = f2bf(Wv[i - 131072]);
    else if (i < 262144) Wob[i - 196608] = f2bf(Wo[i - 196608]);
}

// ------------------- K0b: x[b][c][n] f32 -> xT[b][n][c] bf16 ----------------
__global__ __launch_bounds__(256) void k_xpose(
    const float* __restrict__ x, unsigned short* __restrict__ xT)
{
    __shared__ float tile[64][68];                 // 68: 16B-aligned rows, bank-spread
    const int b  = blockIdx.z;
    const int n0 = blockIdx.x * 64, c0 = blockIdx.y * 64;
    const int t  = threadIdx.x;
    const float* xp = x + ((size_t)b * NC + c0) * NN + n0;
    const int cc = t >> 4, nq = t & 15;
    #pragma unroll
    for (int j = 0; j < 4; ++j) {
        const int c = j * 16 + cc;
        f32x4 v = *(const f32x4*)(xp + (size_t)c * NN + nq * 4);
        *(f32x4*)&tile[c][nq * 4] = v;
    }
    __syncthreads();
    unsigned short* op = xT + ((size_t)b * NN + n0) * NC + c0;
    const int nn0 = t >> 4, cq = t & 15;
    #pragma unroll
    for (int j = 0; j < 4; ++j) {
        const int nn = j * 16 + nn0;
        u16x4 o;
        #pragma unroll
        for (int ii = 0; ii < 4; ++ii) o[ii] = f2bf(tile[cq * 4 + ii][nn]);
        *(u16x4*)(op + (size_t)nn * NC + cq * 4) = o;
    }
}

// ------ K1: [phiQ;phiK^T;phiV] = phi(Wqkv @ x) ; grid = 16*6*32 -------------
// Q,V stored [c][n] (SWAP epilogue: regs span n). K stored [n][c] (no swap).
__global__ __launch_bounds__(256) void k_proj(
    const unsigned short* __restrict__ Wqkv, const unsigned short* __restrict__ xT,
    unsigned short* __restrict__ phiQ, unsigned short* __restrict__ phiKT,
    unsigned short* __restrict__ phiV)
{
    __shared__ char lds[32768];
    const int bid = blockIdx.x;
    const int nt  = bid & 31;
    const int mt  = (bid >> 5) % 6;
    const int b   = bid / 192;
    const unsigned short* A  = Wqkv + mt * 128 * NC;
    const unsigned short* BT = xT + ((size_t)b * NN + nt * 128) * NC;

    const int lane = threadIdx.x & 63;
    const int w    = threadIdx.x >> 6;
    const int wr   = (w >> 1) * 64, wc = (w & 1) * 64;
    const int q4   = (lane >> 4) * 4, c15 = lane & 15;
    const int p    = mt >> 1;                 // 0=Q, 1=K, 2=V

    f32x4 acc[4][4] = {};
    if (p == 1) {
        gemm128<false>(A, NC, BT, NC, 0, 4, lds, lds + 16384, acc);
        // phiKT[n][c]: regs span c -> packed u16x4 along c
        unsigned short* dst = phiKT + (size_t)b * NN * NC;
        const int cb = (mt & 1) * 128 + wr + q4;
        const int nb = nt * 128 + wc + c15;
        #pragma unroll
        for (int m = 0; m < 4; ++m)
            #pragma unroll
            for (int n = 0; n < 4; ++n) {
                u16x4 pk;
                #pragma unroll
                for (int i = 0; i < 4; ++i) pk[i] = f2bf(phi_act(acc[m][n][i]));
                *(u16x4*)(dst + (size_t)(nb + n * 16) * NC + cb + m * 16) = pk;
            }
    } else {
        gemm128<true>(A, NC, BT, NC, 0, 4, lds, lds + 16384, acc);
        // phi{Q,V}[c][n]: SWAP -> regs span n -> packed u16x4 along n
        unsigned short* dst = (p == 0 ? phiQ : phiV) + (size_t)b * NC * NN;
        const int ob = (mt & 1) * 128 + wr + c15;   // col dim = o (c of phi)
        const int nb = nt * 128 + wc + q4;
        #pragma unroll
        for (int m = 0; m < 4; ++m)
            #pragma unroll
            for (int n = 0; n < 4; ++n) {
                u16x4 pk;
                #pragma unroll
                for (int i = 0; i < 4; ++i) pk[i] = f2bf(phi_act(acc[m][n][i]));
                *(u16x4*)(dst + (size_t)(ob + m * 16) * NN + nb + n * 16) = pk;
            }
    }
}

// ------ K2: qvT_part[s][b][d][c] partials, split-K=8 ------------------------
__global__ __launch_bounds__(256) void k_qv(
    const unsigned short* __restrict__ phiQ, const unsigned short* __restrict__ phiV,
    float* __restrict__ qvTp)
{
    __shared__ char lds[32768];
    const int bid = blockIdx.x;                    // 512 blocks
    const int s = bid & 7, nt = (bid >> 3) & 1, mt = (bid >> 4) & 1, b = bid >> 5;
    const unsigned short* A  = phiQ + ((size_t)b * NC + mt * 128) * NN;
    const unsigned short* BT = phiV + ((size_t)b * NC + nt * 128) * NN;
    f32x4 acc[4][4] = {};
    gemm128<false>(A, NN, BT, NN, s * 512, 8, lds, lds + 16384, acc);

    const int lane = threadIdx.x & 63, w = threadIdx.x >> 6;
    const int wr = (w >> 1) * 64, wc = (w & 1) * 64;
    const int q4 = (lane >> 4) * 4, c15 = lane & 15;
    float* dst = qvTp + (((size_t)s * NB + b) << 16);
    const int c0 = mt * 128 + wr + q4;
    const int d0 = nt * 128 + wc + c15;
    #pragma unroll
    for (int m = 0; m < 4; ++m)
        #pragma unroll
        for (int n = 0; n < 4; ++n)
            *(f32x4*)(dst + (size_t)(d0 + n * 16) * NC + c0 + m * 16) = acc[m][n];
}

// ------ K2b: qvT[b][d][c] bf16 = sum_s partials -----------------------------
__global__ __launch_bounds__(256) void k_qvred(
    const float* __restrict__ p, unsigned short* __restrict__ qvT)
{
    const size_t i = (size_t)blockIdx.x * 256 + threadIdx.x;  // 262144 f32x4 units
    const f32x4* pv = (const f32x4*)p;
    f32x4 v = pv[i];
    #pragma unroll
    for (int s = 1; s < 8; ++s) v = v + pv[i + (size_t)s * 262144];
    u16x4 o;
    #pragma unroll
    for (int j = 0; j < 4; ++j) o[j] = f2bf(v[j]);
    ((u16x4*)qvT)[i] = o;
}

// ------ K3: Mb[b][o][d] = Wo @ qv  (SWAP: regs span d) -----------------------
__global__ __launch_bounds__(256) void k_mproj(
    const unsigned short* __restrict__ Wob, const unsigned short* __restrict__ qvT,
    unsigned short* __restrict__ Mb)
{
    __shared__ char lds[32768];
    const int bid = blockIdx.x;                    // 64 blocks
    const int nt = bid & 1, mt = (bid >> 1) & 1, b = bid >> 2;
    const unsigned short* A  = Wob + mt * 128 * NC;
    const unsigned short* BT = qvT + ((size_t)b << 16) + nt * 128 * NC;
    f32x4 acc[4][4] = {};
    gemm128<true>(A, NC, BT, NC, 0, 4, lds, lds + 16384, acc);

    const int lane = threadIdx.x & 63, w = threadIdx.x >> 6;
    const int wr = (w >> 1) * 64, wc = (w & 1) * 64;
    const int q4 = (lane >> 4) * 4, c15 = lane & 15;
    unsigned short* dst = Mb + ((size_t)b << 16);
    const int ob = mt * 128 + wr + c15;
    const int db = nt * 128 + wc + q4;
    #pragma unroll
    for (int m = 0; m < 4; ++m)
        #pragma unroll
        for (int n = 0; n < 4; ++n) {
            u16x4 pk;
            #pragma unroll
            for (int i = 0; i < 4; ++i) pk[i] = f2bf(acc[m][n][i]);
            *(u16x4*)(dst + (size_t)(ob + m * 16) * NC + db + n * 16) = pk;
        }
}

// ------ K4: out[b][o][n] = Mb @ phiK + bo  (SWAP: regs span n, f32x4 stores) -
__global__ __launch_bounds__(256) void k_out(
    const unsigned short* __restrict__ Mb, const unsigned short* __restrict__ phiKT,
    const float* __restrict__ bo, float* __restrict__ out)
{
    __shared__ char lds[32768];
    const int bid = blockIdx.x;                    // 1024 blocks
    const int nt = bid & 31, mt = (bid >> 5) & 1, b = bid >> 6;
    const unsigned short* A  = Mb + ((size_t)b << 16) + mt * 128 * NC;
    const unsigned short* BT = phiKT + (size_t)b * NN * NC + (size_t)nt * 128 * NC;
    f32x4 acc[4][4] = {};
    gemm128<true>(A, NC, BT, NC, 0, 4, lds, lds + 16384, acc);

    const int lane = threadIdx.x & 63, w = threadIdx.x >> 6;
    const int wr = (w >> 1) * 64, wc = (w & 1) * 64;
    const int q4 = (lane >> 4) * 4, c15 = lane & 15;
    float* dst = out + (size_t)b * NC * NN;
    #pragma unroll
    for (int m = 0; m < 4; ++m) {
        const int o  = mt * 128 + wr + m * 16 + c15;
        const float bb = bo[o];
        #pragma unroll
        for (int n = 0; n < 4; ++n) {
            f32x4 v = acc[m][n];
            #pragma unroll
            for (int i = 0; i < 4; ++i) v[i] += bb;
            *(f32x4*)(dst + (size_t)o * NN + nt * 128 + wc + n * 16 + q4) = v;
        }
    }
}

// ---------------------------------------------------------------------------
extern "C" void kernel_launch(void* const* d_in, const int* in_sizes, int n_in,
                              void* d_out, int out_size, void* d_ws, size_t ws_size,
                              hipStream_t stream)
{
    (void)in_sizes; (void)n_in; (void)out_size; (void)ws_size;
    const float* x  = (const float*)d_in[0];
    const float* Wq = (const float*)d_in[1];
    const float* Wk = (const float*)d_in[2];
    const float* Wv = (const float*)d_in[3];
    const float* Wo = (const float*)d_in[4];
    const float* bo = (const float*)d_in[5];
    float* out = (float*)d_out;

    char* ws = (char*)d_ws;
    size_t off = 0;
    auto alloc = [&](size_t bytes) {
        void* p = ws + off;
        off += (bytes + 255) & ~(size_t)255;
        return p;
    };
    unsigned short* xT    = (unsigned short*)alloc((size_t)NB * NN * NC * 2); // 32 MiB
    unsigned short* phiQ  = (unsigned short*)alloc((size_t)NB * NC * NN * 2); // 32 MiB
    unsigned short* phiV  = (unsigned short*)alloc((size_t)NB * NC * NN * 2); // 32 MiB
    unsigned short* phiKT = (unsigned short*)alloc((size_t)NB * NN * NC * 2); // 32 MiB
    unsigned short* qvT   = (unsigned short*)alloc((size_t)NB * NC * NC * 2); //  2 MiB
    unsigned short* Mb    = (unsigned short*)alloc((size_t)NB * NC * NC * 2); //  2 MiB
    unsigned short* Wqkv  = (unsigned short*)alloc((size_t)768 * NC * 2);
    unsigned short* Wob   = (unsigned short*)alloc((size_t)NC * NC * 2);
    float* qvTp = (float*)xT;   // alias: xT dead after k_proj; 8*16*64K*4B = 32 MiB

    k_wconv<<<1024, 256, 0, stream>>>(Wq, Wk, Wv, Wo, Wqkv, Wob);
    k_xpose<<<dim3(NN / 64, NC / 64, NB), dim3(256), 0, stream>>>(x, xT);
    k_proj<<<NB * 6 * 32, 256, 0, stream>>>(Wqkv, xT, phiQ, phiKT, phiV);
    k_qv<<<NB * 2 * 2 * 8, 256, 0, stream>>>(phiQ, phiV, qvTp);
    k_qvred<<<1024, 256, 0, stream>>>(qvTp, qvT);
    k_mproj<<<NB * 2 * 2, 256, 0, stream>>>(Wob, qvT, Mb);
    k_out<<<NB * 2 * 32, 256, 0, stream>>>(Mb, phiKT, bo, out);
}